// Round 1
// baseline (198.425 us; speedup 1.0000x reference)
//
#include <hip/hip_runtime.h>
#include <stdint.h>

// LatticeCharCell: B=4096, M=16, IN=512, H=512
// Pipeline:
//   cvt kernels: build bf16 XH=[input|h0] (4096x1024), Cbf=all_c (65536x512),
//                Wcat=[Wii|Whi; Wig|Whg; Wio|Who; Wlx|0] (2048x1024), Wlc (512x512)
//   k_gemm<false>: C1 = XH @ Wcat^T   (4096x2048 f32)   -- all gate pre-acts
//   k_gemm<true> : lc = Cbf @ Wlc^T with FUSED lattice epilogue -> h1, c

typedef __attribute__((ext_vector_type(8))) short short8;
typedef __attribute__((ext_vector_type(4))) float f32x4;
typedef __attribute__((ext_vector_type(4))) unsigned short us4;

__device__ __forceinline__ unsigned short f2bf(float f) {
  union { float f; unsigned u; } v; v.f = f;
  return (unsigned short)((v.u + 0x7fffu + ((v.u >> 16) & 1u)) >> 16);
}
__device__ __forceinline__ float sigmoidf_(float x) {
  return 1.f / (1.f + __expf(-x));
}

// ---------------- conversion kernels ----------------
__global__ void k_cvt_xh(const float* __restrict__ x, const float* __restrict__ h,
                         unsigned short* __restrict__ out) {
  int t = blockIdx.x * blockDim.x + threadIdx.x;   // 4096*256 threads, 4 cols each
  int b = t >> 8;
  int col = (t & 255) * 4;
  const float* src = (col < 512) ? (x + (size_t)b * 512 + col)
                                 : (h + (size_t)b * 512 + (col - 512));
  f32x4 v = *(const f32x4*)src;
  us4 o;
  o[0] = f2bf(v[0]); o[1] = f2bf(v[1]); o[2] = f2bf(v[2]); o[3] = f2bf(v[3]);
  *(us4*)(out + (size_t)t * 4) = o;
}

__global__ void k_cvt_c(const float* __restrict__ src, unsigned short* __restrict__ out) {
  size_t t = (size_t)blockIdx.x * blockDim.x + threadIdx.x;  // 8388608 threads
  f32x4 v = *(const f32x4*)(src + t * 4);
  us4 o;
  o[0] = f2bf(v[0]); o[1] = f2bf(v[1]); o[2] = f2bf(v[2]); o[3] = f2bf(v[3]);
  *(us4*)(out + t * 4) = o;
}

__global__ void k_cvt_w(const float* __restrict__ Wii, const float* __restrict__ Wig,
                        const float* __restrict__ Wio, const float* __restrict__ Wlx,
                        const float* __restrict__ Whi, const float* __restrict__ Whg,
                        const float* __restrict__ Who, unsigned short* __restrict__ out) {
  int t = blockIdx.x * blockDim.x + threadIdx.x;   // 2048*256 threads
  int row = t >> 8;
  int col = (t & 255) * 4;
  int sec = row >> 9, r = row & 511;
  us4 o;
  if (col < 512) {
    const float* W = sec == 0 ? Wii : sec == 1 ? Wig : sec == 2 ? Wio : Wlx;
    f32x4 v = *(const f32x4*)(W + (size_t)r * 512 + col);
    o[0] = f2bf(v[0]); o[1] = f2bf(v[1]); o[2] = f2bf(v[2]); o[3] = f2bf(v[3]);
  } else if (sec < 3) {
    const float* W = sec == 0 ? Whi : sec == 1 ? Whg : Who;
    f32x4 v = *(const f32x4*)(W + (size_t)r * 512 + (col - 512));
    o[0] = f2bf(v[0]); o[1] = f2bf(v[1]); o[2] = f2bf(v[2]); o[3] = f2bf(v[3]);
  } else {
    o[0] = 0; o[1] = 0; o[2] = 0; o[3] = 0;   // lx row has no h-part
  }
  *(us4*)(out + (size_t)t * 4) = o;
}

__global__ void k_cvt_wlc(const float* __restrict__ src, unsigned short* __restrict__ out) {
  int t = blockIdx.x * blockDim.x + threadIdx.x;   // 65536 threads
  f32x4 v = *(const f32x4*)(src + (size_t)t * 4);
  us4 o;
  o[0] = f2bf(v[0]); o[1] = f2bf(v[1]); o[2] = f2bf(v[2]); o[3] = f2bf(v[3]);
  *(us4*)(out + (size_t)t * 4) = o;
}

// ---------------- GEMM (C = A[M,K] * Bm[N,K]^T), bf16 MFMA ----------------
// 128x128 tile, 4 waves (2x2), each wave 64x64 = 4x4 frags of 16x16, BK=64.
// LDS linear [128][64] bf16; XOR-swizzled k-slots (slot ^= row&7) applied on the
// GLOBAL source of global_load_lds and on the ds_read address (both-sides rule).
template <bool LAT>
__global__ __launch_bounds__(256) void k_gemm(
    const unsigned short* __restrict__ A, const unsigned short* __restrict__ Bm,
    float* __restrict__ C, int Ndim, int Kdim, int nbx,
    const float* __restrict__ C1, const float* __restrict__ all_c,
    const int* __restrict__ num_word,
    const float* __restrict__ b_ii, const float* __restrict__ b_hi,
    const float* __restrict__ b_ig, const float* __restrict__ b_hg,
    const float* __restrict__ b_io, const float* __restrict__ b_ho,
    const float* __restrict__ b_lx, const float* __restrict__ b_lc,
    float* __restrict__ outH, float* __restrict__ outC) {
  __shared__ unsigned short As[128 * 64];
  __shared__ unsigned short Bs[128 * 64];
  const int tid = threadIdx.x;
  const int lane = tid & 63, wid = tid >> 6;
  const int wr = wid >> 1, wc = wid & 1;
  const int l15 = lane & 15, lhi = lane >> 4;
  const int brow = blockIdx.x / nbx, bcol = blockIdx.x % nbx;
  const int m0 = brow * 128, n0 = bcol * 128;

  f32x4 acc[4][4];
#pragma unroll
  for (int i = 0; i < 4; ++i)
#pragma unroll
    for (int j = 0; j < 4; ++j) acc[i][j] = (f32x4){0.f, 0.f, 0.f, 0.f};

  for (int k0 = 0; k0 < Kdim; k0 += 64) {
#pragma unroll
    for (int q = 0; q < 4; ++q) {
      const int cb = q * 256 + wid * 64;        // wave-uniform chunk base
      const int chunk = cb + lane;
      const int row = chunk >> 3, slot = chunk & 7;
      const int kk = k0 + ((slot ^ (row & 7)) << 3);  // inverse-swizzled source
      __builtin_amdgcn_global_load_lds(
          (const __attribute__((address_space(1))) unsigned int*)(A + (size_t)(m0 + row) * Kdim + kk),
          (__attribute__((address_space(3))) unsigned int*)(As + cb * 8), 16, 0, 0);
      __builtin_amdgcn_global_load_lds(
          (const __attribute__((address_space(1))) unsigned int*)(Bm + (size_t)(n0 + row) * Kdim + kk),
          (__attribute__((address_space(3))) unsigned int*)(Bs + cb * 8), 16, 0, 0);
    }
    __syncthreads();
    const char* Ab = (const char*)As;
    const char* Bb = (const char*)Bs;
    const int swz = (lane & 7) << 4;
#pragma unroll
    for (int s = 0; s < 2; ++s) {
      short8 av[4], bv[4];
#pragma unroll
      for (int mi = 0; mi < 4; ++mi) {
        const int row = wr * 64 + mi * 16 + l15;
        av[mi] = *(const short8*)(Ab + row * 128 + ((s * 64 + lhi * 16) ^ swz));
      }
#pragma unroll
      for (int ni = 0; ni < 4; ++ni) {
        const int row = wc * 64 + ni * 16 + l15;
        bv[ni] = *(const short8*)(Bb + row * 128 + ((s * 64 + lhi * 16) ^ swz));
      }
#pragma unroll
      for (int mi = 0; mi < 4; ++mi)
#pragma unroll
        for (int ni = 0; ni < 4; ++ni)
          acc[mi][ni] = __builtin_amdgcn_mfma_f32_16x16x32_bf16(av[mi], bv[ni], acc[mi][ni], 0, 0, 0);
    }
    __syncthreads();
  }

  if (!LAT) {
    // plain store: C/D layout col=lane&15, row=(lane>>4)*4+j
#pragma unroll
    for (int mi = 0; mi < 4; ++mi) {
      const int gr = m0 + wr * 64 + mi * 16 + lhi * 4;
#pragma unroll
      for (int ni = 0; ni < 4; ++ni) {
        const int gc = n0 + wc * 64 + ni * 16 + l15;
#pragma unroll
        for (int j = 0; j < 4; ++j) C[(size_t)(gr + j) * Ndim + gc] = acc[mi][ni][j];
      }
    }
  } else {
    // rows = b*16 + m : each 16-row fragment is exactly one batch, all 16 words.
    const int b0 = m0 >> 4;
#pragma unroll
    for (int mi = 0; mi < 4; ++mi) {
      const int b = b0 + wr * 4 + mi;
      const int nw = num_word[b];
#pragma unroll
      for (int ni = 0; ni < 4; ++ni) {
        const int hc = n0 + wc * 64 + ni * 16 + l15;
        const float lcb = b_lc[hc];
        const float lxv = C1[(size_t)b * 2048 + 1536 + hc] + b_lx[hc];
        float se = 0.f, sew = 0.f;
#pragma unroll
        for (int j = 0; j < 4; ++j) {
          const int m = lhi * 4 + j;
          const float ib = sigmoidf_(lxv + acc[mi][ni][j] + lcb);
          const float e = (m < nw) ? __expf(ib) : 0.f;
          const float w = all_c[((size_t)b * 16 + m) * 512 + hc];
          se += e;
          sew += e * w;
        }
        se += __shfl_xor(se, 16, 64);
        sew += __shfl_xor(sew, 16, 64);
        se += __shfl_xor(se, 32, 64);
        sew += __shfl_xor(sew, 32, 64);
        if (lhi == 0) {
          const size_t base = (size_t)b * 2048;
          const float ig = sigmoidf_(C1[base + hc] + b_ii[hc] + b_hi[hc]);
          const float g  = tanhf(C1[base + 512 + hc] + b_ig[hc] + b_hg[hc]);
          const float og = sigmoidf_(C1[base + 1024 + hc] + b_io[hc] + b_ho[hc]);
          const float ei = __expf(ig);
          const float denom = ei + se;               // nw==0 -> denom=ei, c=g
          const float cc = (sew + ei * g) / denom;
          outH[(size_t)b * 512 + hc] = og * tanhf(cc);
          outC[(size_t)b * 512 + hc] = cc;
        }
      }
    }
  }
}

extern "C" void kernel_launch(void* const* d_in, const int* in_sizes, int n_in,
                              void* d_out, int out_size, void* d_ws, size_t ws_size,
                              hipStream_t stream) {
  const float* input    = (const float*)d_in[0];
  const float* h0       = (const float*)d_in[1];
  const float* all_c    = (const float*)d_in[3];
  const int*   num_word = (const int*)d_in[4];
  const float* W_ii = (const float*)d_in[5];  const float* b_ii = (const float*)d_in[6];
  const float* W_hi = (const float*)d_in[7];  const float* b_hi = (const float*)d_in[8];
  const float* W_ig = (const float*)d_in[13]; const float* b_ig = (const float*)d_in[14];
  const float* W_hg = (const float*)d_in[15]; const float* b_hg = (const float*)d_in[16];
  const float* W_io = (const float*)d_in[17]; const float* b_io = (const float*)d_in[18];
  const float* W_ho = (const float*)d_in[19]; const float* b_ho = (const float*)d_in[20];
  const float* W_lx = (const float*)d_in[21]; const float* b_lx = (const float*)d_in[22];
  const float* W_lc = (const float*)d_in[23]; const float* b_lc = (const float*)d_in[24];

  char* ws = (char*)d_ws;
  unsigned short* XH   = (unsigned short*)(ws);               // 4096x1024 bf16 = 8 MB
  unsigned short* Cbf  = (unsigned short*)(ws + 8388608);     // 65536x512 bf16 = 64 MB
  unsigned short* Wcat = (unsigned short*)(ws + 75497472);    // 2048x1024 bf16 = 4 MB
  unsigned short* Wlc  = (unsigned short*)(ws + 79691776);    // 512x512 bf16 = 0.5 MB
  float*          C1   = (float*)(ws + 80216064);             // 4096x2048 f32 = 32 MB

  float* outH = (float*)d_out;
  float* outC = outH + (size_t)4096 * 512;

  k_cvt_xh<<<4096, 256, 0, stream>>>(input, h0, XH);
  k_cvt_c<<<32768, 256, 0, stream>>>(all_c, Cbf);
  k_cvt_w<<<2048, 256, 0, stream>>>(W_ii, W_ig, W_io, W_lx, W_hi, W_hg, W_ho, Wcat);
  k_cvt_wlc<<<256, 256, 0, stream>>>(W_lc, Wlc);

  // C1 = XH @ Wcat^T : M=4096, N=2048, K=1024 -> grid 32*16
  k_gemm<false><<<512, 256, 0, stream>>>(XH, Wcat, C1, 2048, 1024, 16,
      nullptr, nullptr, nullptr, nullptr, nullptr, nullptr, nullptr, nullptr,
      nullptr, nullptr, nullptr, nullptr, nullptr);

  // lc GEMM + fused lattice epilogue : M=65536, N=512, K=512 -> grid 512*4
  k_gemm<true><<<2048, 256, 0, stream>>>(Cbf, Wlc, nullptr, 512, 512, 4,
      C1, all_c, num_word, b_ii, b_hi, b_ig, b_hg, b_io, b_ho, b_lx, b_lc,
      outH, outC);
}

// Round 2
// 177.093 us; speedup vs baseline: 1.1205x; 1.1205x over previous
//
#include <hip/hip_runtime.h>
#include <stdint.h>

// LatticeCharCell: B=4096, M=16, IN=512, H=512
// Pipeline:
//   cvt kernels: build bf16 XH=[input|h0] (4096x1024), Cbf=all_c (65536x512),
//                Wcat=[Wii|Whi; Wig|Whg; Wio|Who; Wlx|0] (2048x1024), Wlc (512x512)
//   k_gemm<false>: C1 = XH @ Wcat^T   (4096x2048 f32)   -- all gate pre-acts
//   k_gemm<true> : lc = Cbf @ Wlc^T with FUSED lattice epilogue -> h1, c
// R2: 2-phase double-buffered K-loop (stage t+1 before compute t, one barrier
//     per k-step) + chunked XCD blockIdx swizzle + fast tanh in epilogue.

typedef __attribute__((ext_vector_type(8))) short short8;
typedef __attribute__((ext_vector_type(4))) float f32x4;
typedef __attribute__((ext_vector_type(4))) unsigned short us4;

__device__ __forceinline__ unsigned short f2bf(float f) {
  union { float f; unsigned u; } v; v.f = f;
  return (unsigned short)((v.u + 0x7fffu + ((v.u >> 16) & 1u)) >> 16);
}
__device__ __forceinline__ float sigmoidf_(float x) {
  return 1.f / (1.f + __expf(-x));
}
__device__ __forceinline__ float fast_tanh(float x) {
  float e = __expf(-2.f * fmaxf(x, -30.f));
  return (1.f - e) / (1.f + e);
}

// ---------------- conversion kernels ----------------
__global__ void k_cvt_xh(const float* __restrict__ x, const float* __restrict__ h,
                         unsigned short* __restrict__ out) {
  int t = blockIdx.x * blockDim.x + threadIdx.x;   // 4096*256 threads, 4 cols each
  int b = t >> 8;
  int col = (t & 255) * 4;
  const float* src = (col < 512) ? (x + (size_t)b * 512 + col)
                                 : (h + (size_t)b * 512 + (col - 512));
  f32x4 v = *(const f32x4*)src;
  us4 o;
  o[0] = f2bf(v[0]); o[1] = f2bf(v[1]); o[2] = f2bf(v[2]); o[3] = f2bf(v[3]);
  *(us4*)(out + (size_t)t * 4) = o;
}

__global__ void k_cvt_c(const float* __restrict__ src, unsigned short* __restrict__ out) {
  size_t t = (size_t)blockIdx.x * blockDim.x + threadIdx.x;  // 8388608 threads
  f32x4 v = *(const f32x4*)(src + t * 4);
  us4 o;
  o[0] = f2bf(v[0]); o[1] = f2bf(v[1]); o[2] = f2bf(v[2]); o[3] = f2bf(v[3]);
  *(us4*)(out + t * 4) = o;
}

__global__ void k_cvt_w(const float* __restrict__ Wii, const float* __restrict__ Wig,
                        const float* __restrict__ Wio, const float* __restrict__ Wlx,
                        const float* __restrict__ Whi, const float* __restrict__ Whg,
                        const float* __restrict__ Who, unsigned short* __restrict__ out) {
  int t = blockIdx.x * blockDim.x + threadIdx.x;   // 2048*256 threads
  int row = t >> 8;
  int col = (t & 255) * 4;
  int sec = row >> 9, r = row & 511;
  us4 o;
  if (col < 512) {
    const float* W = sec == 0 ? Wii : sec == 1 ? Wig : sec == 2 ? Wio : Wlx;
    f32x4 v = *(const f32x4*)(W + (size_t)r * 512 + col);
    o[0] = f2bf(v[0]); o[1] = f2bf(v[1]); o[2] = f2bf(v[2]); o[3] = f2bf(v[3]);
  } else if (sec < 3) {
    const float* W = sec == 0 ? Whi : sec == 1 ? Whg : Who;
    f32x4 v = *(const f32x4*)(W + (size_t)r * 512 + (col - 512));
    o[0] = f2bf(v[0]); o[1] = f2bf(v[1]); o[2] = f2bf(v[2]); o[3] = f2bf(v[3]);
  } else {
    o[0] = 0; o[1] = 0; o[2] = 0; o[3] = 0;   // lx row has no h-part
  }
  *(us4*)(out + (size_t)t * 4) = o;
}

__global__ void k_cvt_wlc(const float* __restrict__ src, unsigned short* __restrict__ out) {
  int t = blockIdx.x * blockDim.x + threadIdx.x;   // 65536 threads
  f32x4 v = *(const f32x4*)(src + (size_t)t * 4);
  us4 o;
  o[0] = f2bf(v[0]); o[1] = f2bf(v[1]); o[2] = f2bf(v[2]); o[3] = f2bf(v[3]);
  *(us4*)(out + (size_t)t * 4) = o;
}

// ---------------- GEMM (C = A[M,K] * Bm[N,K]^T), bf16 MFMA ----------------
// 128x128 tile, 4 waves (2x2), each wave 64x64 = 4x4 frags of 16x16, BK=64.
// 2-phase double-buffer: stage k-tile t+1, compute k-tile t, one barrier/step.
// XOR-swizzled k-slots (slot ^= row&7) applied on the GLOBAL source of
// global_load_lds and on the ds_read address (both-sides rule).
template <bool LAT>
__global__ __launch_bounds__(256) void k_gemm(
    const unsigned short* __restrict__ A, const unsigned short* __restrict__ Bm,
    float* __restrict__ C, int Ndim, int Kdim, int nbx,
    const float* __restrict__ C1, const float* __restrict__ all_c,
    const int* __restrict__ num_word,
    const float* __restrict__ b_ii, const float* __restrict__ b_hi,
    const float* __restrict__ b_ig, const float* __restrict__ b_hg,
    const float* __restrict__ b_io, const float* __restrict__ b_ho,
    const float* __restrict__ b_lx, const float* __restrict__ b_lc,
    float* __restrict__ outH, float* __restrict__ outC) {
  __shared__ unsigned short As[2][128 * 64];
  __shared__ unsigned short Bs[2][128 * 64];
  const int tid = threadIdx.x;
  const int lane = tid & 63, wid = tid >> 6;
  const int wr = wid >> 1, wc = wid & 1;
  const int l15 = lane & 15, lhi = lane >> 4;

  // chunked XCD swizzle: gridDim.x % 8 == 0 for both launches
  const int chunk = gridDim.x >> 3;
  const int bid = (blockIdx.x & 7) * chunk + (blockIdx.x >> 3);
  const int brow = bid / nbx, bcol = bid % nbx;
  const int m0 = brow * 128, n0 = bcol * 128;

  f32x4 acc[4][4];
#pragma unroll
  for (int i = 0; i < 4; ++i)
#pragma unroll
    for (int j = 0; j < 4; ++j) acc[i][j] = (f32x4){0.f, 0.f, 0.f, 0.f};

  // per-thread staging geometry (wave-uniform LDS base + lane*16B)
  const int cb0 = wid * 64;      // chunk base within a 256-chunk quarter
  auto stage = [&](int buf, int k0) {
#pragma unroll
    for (int q = 0; q < 4; ++q) {
      const int cb = q * 256 + cb0;
      const int chunkid = cb + lane;
      const int row = chunkid >> 3, slot = chunkid & 7;
      const int kk = k0 + ((slot ^ (row & 7)) << 3);  // inverse-swizzled source
      __builtin_amdgcn_global_load_lds(
          (const __attribute__((address_space(1))) unsigned int*)(A + (size_t)(m0 + row) * Kdim + kk),
          (__attribute__((address_space(3))) unsigned int*)(As[buf] + cb * 8), 16, 0, 0);
      __builtin_amdgcn_global_load_lds(
          (const __attribute__((address_space(1))) unsigned int*)(Bm + (size_t)(n0 + row) * Kdim + kk),
          (__attribute__((address_space(3))) unsigned int*)(Bs[buf] + cb * 8), 16, 0, 0);
    }
  };

  const int nt = Kdim >> 6;
  stage(0, 0);
  __syncthreads();

  const int swz = (lane & 7) << 4;
  for (int t = 0; t < nt; ++t) {
    const int cur = t & 1;
    if (t + 1 < nt) stage(cur ^ 1, (t + 1) << 6);   // prefetch next k-tile
    const char* Ab = (const char*)As[cur];
    const char* Bb = (const char*)Bs[cur];
#pragma unroll
    for (int s = 0; s < 2; ++s) {
      short8 av[4], bv[4];
#pragma unroll
      for (int mi = 0; mi < 4; ++mi) {
        const int row = wr * 64 + mi * 16 + l15;
        av[mi] = *(const short8*)(Ab + row * 128 + ((s * 64 + lhi * 16) ^ swz));
      }
#pragma unroll
      for (int ni = 0; ni < 4; ++ni) {
        const int row = wc * 64 + ni * 16 + l15;
        bv[ni] = *(const short8*)(Bb + row * 128 + ((s * 64 + lhi * 16) ^ swz));
      }
#pragma unroll
      for (int mi = 0; mi < 4; ++mi)
#pragma unroll
        for (int ni = 0; ni < 4; ++ni)
          acc[mi][ni] = __builtin_amdgcn_mfma_f32_16x16x32_bf16(av[mi], bv[ni], acc[mi][ni], 0, 0, 0);
    }
    __syncthreads();   // drains vmcnt(0): next tile staged; buffers safe to swap
  }

  if (!LAT) {
    // plain store: C/D layout col=lane&15, row=(lane>>4)*4+j
#pragma unroll
    for (int mi = 0; mi < 4; ++mi) {
      const int gr = m0 + wr * 64 + mi * 16 + lhi * 4;
#pragma unroll
      for (int ni = 0; ni < 4; ++ni) {
        const int gc = n0 + wc * 64 + ni * 16 + l15;
#pragma unroll
        for (int j = 0; j < 4; ++j) C[(size_t)(gr + j) * Ndim + gc] = acc[mi][ni][j];
      }
    }
  } else {
    // rows = b*16 + m : each 16-row fragment is exactly one batch, all 16 words.
    const int b0 = m0 >> 4;
#pragma unroll
    for (int mi = 0; mi < 4; ++mi) {
      const int b = b0 + wr * 4 + mi;
      const int nw = num_word[b];
#pragma unroll
      for (int ni = 0; ni < 4; ++ni) {
        const int hc = n0 + wc * 64 + ni * 16 + l15;
        const float lcb = b_lc[hc];
        const float lxv = C1[(size_t)b * 2048 + 1536 + hc] + b_lx[hc];
        float se = 0.f, sew = 0.f;
#pragma unroll
        for (int j = 0; j < 4; ++j) {
          const int m = lhi * 4 + j;
          const float ib = sigmoidf_(lxv + acc[mi][ni][j] + lcb);
          const float e = (m < nw) ? __expf(ib) : 0.f;
          const float w = all_c[((size_t)b * 16 + m) * 512 + hc];
          se += e;
          sew += e * w;
        }
        se += __shfl_xor(se, 16, 64);
        sew += __shfl_xor(sew, 16, 64);
        se += __shfl_xor(se, 32, 64);
        sew += __shfl_xor(sew, 32, 64);
        if (lhi == 0) {
          const size_t base = (size_t)b * 2048;
          const float ig = sigmoidf_(C1[base + hc] + b_ii[hc] + b_hi[hc]);
          const float g  = fast_tanh(C1[base + 512 + hc] + b_ig[hc] + b_hg[hc]);
          const float og = sigmoidf_(C1[base + 1024 + hc] + b_io[hc] + b_ho[hc]);
          const float ei = __expf(ig);
          const float denom = ei + se;               // nw==0 -> denom=ei, c=g
          const float cc = (sew + ei * g) / denom;
          outH[(size_t)b * 512 + hc] = og * fast_tanh(cc);
          outC[(size_t)b * 512 + hc] = cc;
        }
      }
    }
  }
}

extern "C" void kernel_launch(void* const* d_in, const int* in_sizes, int n_in,
                              void* d_out, int out_size, void* d_ws, size_t ws_size,
                              hipStream_t stream) {
  const float* input    = (const float*)d_in[0];
  const float* h0       = (const float*)d_in[1];
  const float* all_c    = (const float*)d_in[3];
  const int*   num_word = (const int*)d_in[4];
  const float* W_ii = (const float*)d_in[5];  const float* b_ii = (const float*)d_in[6];
  const float* W_hi = (const float*)d_in[7];  const float* b_hi = (const float*)d_in[8];
  const float* W_ig = (const float*)d_in[13]; const float* b_ig = (const float*)d_in[14];
  const float* W_hg = (const float*)d_in[15]; const float* b_hg = (const float*)d_in[16];
  const float* W_io = (const float*)d_in[17]; const float* b_io = (const float*)d_in[18];
  const float* W_ho = (const float*)d_in[19]; const float* b_ho = (const float*)d_in[20];
  const float* W_lx = (const float*)d_in[21]; const float* b_lx = (const float*)d_in[22];
  const float* W_lc = (const float*)d_in[23]; const float* b_lc = (const float*)d_in[24];

  char* ws = (char*)d_ws;
  unsigned short* XH   = (unsigned short*)(ws);               // 4096x1024 bf16 = 8 MB
  unsigned short* Cbf  = (unsigned short*)(ws + 8388608);     // 65536x512 bf16 = 64 MB
  unsigned short* Wcat = (unsigned short*)(ws + 75497472);    // 2048x1024 bf16 = 4 MB
  unsigned short* Wlc  = (unsigned short*)(ws + 79691776);    // 512x512 bf16 = 0.5 MB
  float*          C1   = (float*)(ws + 80216064);             // 4096x2048 f32 = 32 MB

  float* outH = (float*)d_out;
  float* outC = outH + (size_t)4096 * 512;

  k_cvt_xh<<<4096, 256, 0, stream>>>(input, h0, XH);
  k_cvt_c<<<32768, 256, 0, stream>>>(all_c, Cbf);
  k_cvt_w<<<2048, 256, 0, stream>>>(W_ii, W_ig, W_io, W_lx, W_hi, W_hg, W_ho, Wcat);
  k_cvt_wlc<<<256, 256, 0, stream>>>(W_lc, Wlc);

  // C1 = XH @ Wcat^T : M=4096, N=2048, K=1024 -> grid 32*16
  k_gemm<false><<<512, 256, 0, stream>>>(XH, Wcat, C1, 2048, 1024, 16,
      nullptr, nullptr, nullptr, nullptr, nullptr, nullptr, nullptr, nullptr,
      nullptr, nullptr, nullptr, nullptr, nullptr);

  // lc GEMM + fused lattice epilogue : M=65536, N=512, K=512 -> grid 512*4
  k_gemm<true><<<2048, 256, 0, stream>>>(Cbf, Wlc, nullptr, 512, 512, 4,
      C1, all_c, num_word, b_ii, b_hi, b_ig, b_hg, b_io, b_ho, b_lx, b_lc,
      outH, outC);
}